// Round 1
// 603.522 us; speedup vs baseline: 1.0553x; 1.0553x over previous
//
#include <hip/hip_runtime.h>
#include <math.h>

#define NCOL 500000
#define R 32
#define NDIM 3
#define B 1024
#define ETA 0.01f

// ---------------------------------------------------------------------------
// k_copy: out[d] = v_d  (the 384 MB HBM-bound part; touched rows overwritten
// later by k_apply). One float4 per array per thread.
// ---------------------------------------------------------------------------
__global__ void k_copy(const float4* __restrict__ v0, const float4* __restrict__ v1,
                       const float4* __restrict__ v2, float4* __restrict__ out) {
    const int N4 = NCOL * R / 4;  // 4,000,000
    int i = blockIdx.x * blockDim.x + threadIdx.x;
    if (i < N4) {
        out[i]          = v0[i];
        out[N4 + i]     = v1[i];
        out[2 * N4 + i] = v2[i];
    }
}

// ---------------------------------------------------------------------------
// k_coeff: per-sample scalars from pristine v.
//   A[d] = prod_r g_d[r];  P = A0*A1*A2;  phi = sum_r L[r]*g0*g1*g2
//   wi = 0.5/phi * tanh(phi/2);  ki = vals - 0.5;  Q[d] = P/A[d]
// One 32-lane group (lane = r) per sample; 8 samples per 256-thread block.
// ---------------------------------------------------------------------------
__global__ void k_coeff(const int* __restrict__ entries, const int* __restrict__ vals,
                        const float* __restrict__ v0, const float* __restrict__ v1,
                        const float* __restrict__ v2, const float* __restrict__ L,
                        float* __restrict__ Pw, float* __restrict__ Ww,
                        float* __restrict__ Kw, float* __restrict__ Qw,
                        float* __restrict__ sumLw) {
    int tid = threadIdx.x;
    int b = blockIdx.x * 8 + (tid >> 5);
    int r = tid & 31;
    float Lr = L[r];
    int c0 = entries[b * 3 + 0];
    int c1 = entries[b * 3 + 1];
    int c2 = entries[b * 3 + 2];
    float g0 = v0[(size_t)c0 * R + r];
    float g1 = v1[(size_t)c1 * R + r];
    float g2 = v2[(size_t)c2 * R + r];
    float a0 = g0, a1 = g1, a2 = g2;
    float ph = Lr * g0 * g1 * g2;
    float sl = Lr;
    for (int m = 16; m >= 1; m >>= 1) {
        a0 *= __shfl_xor(a0, m, 32);
        a1 *= __shfl_xor(a1, m, 32);
        a2 *= __shfl_xor(a2, m, 32);
        ph += __shfl_xor(ph, m, 32);
        sl += __shfl_xor(sl, m, 32);
    }
    if (r == 0) {
        float Pb = a0 * a1 * a2;
        float w = 0.5f / ph * tanhf(0.5f * ph);
        Pw[b] = Pb;
        Ww[b] = w;
        Kw[b] = (float)vals[b] - 0.5f;
        Qw[0 * B + b] = Pb / a0;
        Qw[1 * B + b] = Pb / a1;
        Qw[2 * B + b] = Pb / a2;
        if (b == 0) sumLw[0] = sl;
    }
}

// ---------------------------------------------------------------------------
// k_links: for each (d,b), find the next sample (ascending b) hitting the same
// column, and whether b is the first hit. Collisions are rare (~1/dim) but must
// be applied in b-order.
// LDS-staged: the whole entries table (12 KB) is loaded once per block; the
// per-thread scan then reads LDS. Within a wave all 64 lanes share d and scan
// the same j, so each iteration's LDS read is a same-address broadcast
// (conflict-free, ~4-6 cyc/iter) instead of a serialized global-load chain
// (~340 cyc/iter measured in the previous version).
// ---------------------------------------------------------------------------
__global__ __launch_bounds__(256) void k_links(const int* __restrict__ entries,
                                               int* __restrict__ nxt,
                                               int* __restrict__ first) {
    __shared__ int se[B * NDIM];  // 12 KB
    int tid = threadIdx.x;
    for (int i = tid; i < B * NDIM; i += 256) se[i] = entries[i];
    __syncthreads();
    int t = blockIdx.x * 256 + tid;
    if (t >= NDIM * B) return;
    int d = t / B, b = t - d * B;
    int col = se[b * 3 + d];
    int nx = -1, fi = 1;
    for (int j = 0; j < B; ++j) {
        if (j == b) continue;
        if (se[j * 3 + d] == col) {
            if (j < b) fi = 0;
            else { nx = j; break; }  // ascending scan: first j>b match
        }
    }
    nxt[t] = nx;
    first[t] = fi;
}

// ---------------------------------------------------------------------------
// k_apply: one thread per (d, b, r). First-hit threads walk the chain applying
//   S <- (1-eta)S + eta*(Q_d L_r)^2 * w
//   T <- (1-eta)T + eta*(k - P*(sumL-L_r)*w) * Q_d L_r
// in b-order, then write out[d][col] = S/T (overwriting the copy).
// ---------------------------------------------------------------------------
__global__ void k_apply(const int* __restrict__ entries,
                        const float* __restrict__ S0, const float* __restrict__ S1,
                        const float* __restrict__ S2,
                        const float* __restrict__ T0, const float* __restrict__ T1,
                        const float* __restrict__ T2,
                        const float* __restrict__ L,
                        const float* __restrict__ Pw, const float* __restrict__ Ww,
                        const float* __restrict__ Kw, const float* __restrict__ Qw,
                        const float* __restrict__ sumLw,
                        const int* __restrict__ nxt, const int* __restrict__ first,
                        float* __restrict__ out) {
    int t = blockIdx.x * blockDim.x + threadIdx.x;  // ((d*B)+b)*32 + r
    int r = t & 31;
    int db = t >> 5;
    if (db >= NDIM * B) return;
    if (!first[db]) return;  // chain handled by first hit
    int d = db / B, b = db - d * B;
    int col = entries[b * 3 + d];
    const float* Sarr = (d == 0) ? S0 : ((d == 1) ? S1 : S2);
    const float* Tarr = (d == 0) ? T0 : ((d == 1) ? T1 : T2);
    float Lr = L[r];
    float dv = sumLw[0] - Lr;  // dvec[b,r] = P[b]*dv
    float s  = Sarr[(size_t)col * R + r];
    float tt = Tarr[(size_t)col * R + r];
    int bb = b;
    while (bb != -1) {
        float c = Qw[d * B + bb] * Lr;
        float w = Ww[bb];
        float updS = c * c * w;
        float updT = (Kw[bb] - Pw[bb] * dv * w) * c;
        s  = (1.0f - ETA) * s  + ETA * updS;
        tt = (1.0f - ETA) * tt + ETA * updT;
        bb = nxt[d * B + bb];
    }
    out[((size_t)d * NCOL + col) * R + r] = s / tt;
}

extern "C" void kernel_launch(void* const* d_in, const int* in_sizes, int n_in,
                              void* d_out, int out_size, void* d_ws, size_t ws_size,
                              hipStream_t stream) {
    const int*   entries = (const int*)d_in[0];
    const int*   vals    = (const int*)d_in[1];
    const float* v0      = (const float*)d_in[2];
    const float* v1      = (const float*)d_in[3];
    const float* v2      = (const float*)d_in[4];
    const float* L       = (const float*)d_in[5];
    const float* S0      = (const float*)d_in[6];
    const float* S1      = (const float*)d_in[7];
    const float* S2      = (const float*)d_in[8];
    const float* T0      = (const float*)d_in[9];
    const float* T1      = (const float*)d_in[10];
    const float* T2      = (const float*)d_in[11];
    float* out = (float*)d_out;

    // workspace layout (floats): P[B], W[B], K[B], Q[3B], sumL[1] (+pad), then ints
    float* wsf  = (float*)d_ws;
    float* Pw   = wsf;
    float* Ww   = wsf + B;
    float* Kw   = wsf + 2 * B;
    float* Qw   = wsf + 3 * B;
    float* sumL = wsf + 6 * B;
    int*   nxt  = (int*)(wsf + 6 * B + 64);
    int*   fst  = nxt + NDIM * B;

    const int N4 = NCOL * R / 4;  // 4,000,000 float4 per array
    k_copy <<<(N4 + 255) / 256, 256, 0, stream>>>((const float4*)v0, (const float4*)v1,
                                                  (const float4*)v2, (float4*)out);
    k_coeff<<<B / 8, 256, 0, stream>>>(entries, vals, v0, v1, v2, L, Pw, Ww, Kw, Qw, sumL);
    k_links<<<(NDIM * B + 255) / 256, 256, 0, stream>>>(entries, nxt, fst);
    k_apply<<<NDIM * B * 32 / 256, 256, 0, stream>>>(entries, S0, S1, S2, T0, T1, T2, L,
                                                     Pw, Ww, Kw, Qw, sumL, nxt, fst, out);
}